// Round 8
// baseline (163.192 us; speedup 1.0000x reference)
//
#include <hip/hip_runtime.h>
#include <cstddef>
#include <cstdint>

// ReBased linear attention, round 8.
// r7 post-mortem: attn grid-limited (512 blocks = 2/CU) + 1-step prefetch with
// vmcnt(0) drain covers only ~300 of ~900cy HBM latency. Changes:
//  - attn: unpaired q-tiles (grid 1024), Q frags direct from global (no qhl LDS
//    -> 45KB LDS, 3 blocks/CU), triple-buffered K/V with 2-ahead prefetch and
//    counted vmcnt(3) (T4: never drain to 0 mid-loop).
//  - v/o GEMMs: BN=64 -> grid 1024 = 4 blocks/CU.

typedef __attribute__((ext_vector_type(8)))  __bf16 bf16x8;
typedef __attribute__((ext_vector_type(4)))  __bf16 bf16x4;
typedef __attribute__((ext_vector_type(4)))  float  f32x4;
typedef __attribute__((ext_vector_type(8)))  unsigned short ushort8;
typedef __attribute__((ext_vector_type(4)))  unsigned short ushort4v;

__device__ __forceinline__ unsigned short f2b(float f) {
    union { float f; unsigned u; } v; v.f = f;
    unsigned r = v.u + 0x7FFFu + ((v.u >> 16) & 1u);   // RNE
    return (unsigned short)(r >> 16);
}
__device__ __forceinline__ float b2f(unsigned short b) {
    union { unsigned u; float f; } v; v.u = ((unsigned)b) << 16;
    return v.f;
}

typedef const __attribute__((address_space(1))) void* gas_ptr;
typedef __attribute__((address_space(3))) void* las_ptr;

__device__ __forceinline__ void gload_lds16(const unsigned short* g, unsigned short* l) {
    // 16B/lane; LDS dest = wave-uniform base + lane*16
    __builtin_amdgcn_global_load_lds((gas_ptr)g, (las_ptr)l, 16, 0, 0);
}

// ---------------- bf16 MFMA GEMM: C[M][N] = A[M][K] @ W[N][K]^T ----------------
// 256 threads = 4 waves (2x2). OUTMODE: 0=f32, 1=bf16, 2=bf16 vT scatter.
template <int BM, int BN, int OUTMODE>
__global__ __launch_bounds__(256) void gemm_mfma(const unsigned short* __restrict__ A,
                                                 const unsigned short* __restrict__ W,
                                                 void* __restrict__ Cout,
                                                 int M, int N, int K) {
    constexpr int BK = 64;
    constexpr int MF = BM / 32;
    constexpr int NF = BN / 32;
    __shared__ __align__(16) unsigned short As[BM * BK];
    __shared__ __align__(16) unsigned short Bs[BN * BK];

    const int t = threadIdx.x;
    const int wid = t >> 6, lane = t & 63;
    const int m0 = blockIdx.x * BM, n0 = blockIdx.y * BN;
    const int wrow = (wid >> 1) * (BM / 2);
    const int wcol = (wid & 1) * (BN / 2);
    const int lr = lane & 15, lk = (lane >> 4) * 8;

    f32x4 acc[MF][NF];
#pragma unroll
    for (int m = 0; m < MF; ++m)
#pragma unroll
        for (int n = 0; n < NF; ++n) acc[m][n] = (f32x4){0.f, 0.f, 0.f, 0.f};

    const unsigned short* Ag = A + (size_t)m0 * K;
    const unsigned short* Wg = W + (size_t)n0 * K;

    for (int k0 = 0; k0 < K; k0 += BK) {
        __syncthreads();
#pragma unroll
        for (int i = 0; i < BM / 32; ++i) {
            const int e = (i * 256 + wid * 64 + lane) * 8;
            gload_lds16(Ag + (size_t)(e >> 6) * K + k0 + (e & 63),
                        As + (size_t)(i * 256 + wid * 64) * 8);
        }
#pragma unroll
        for (int i = 0; i < BN / 32; ++i) {
            const int e = (i * 256 + wid * 64 + lane) * 8;
            gload_lds16(Wg + (size_t)(e >> 6) * K + k0 + (e & 63),
                        Bs + (size_t)(i * 256 + wid * 64) * 8);
        }
        __syncthreads();

#pragma unroll
        for (int kk = 0; kk < BK; kk += 32) {
            bf16x8 af[MF], bf[NF];
#pragma unroll
            for (int m = 0; m < MF; ++m)
                af[m] = *(const bf16x8*)&As[(wrow + m * 16 + lr) * BK + kk + lk];
#pragma unroll
            for (int n = 0; n < NF; ++n)
                bf[n] = *(const bf16x8*)&Bs[(wcol + n * 16 + lr) * BK + kk + lk];
#pragma unroll
            for (int m = 0; m < MF; ++m)
#pragma unroll
                for (int n = 0; n < NF; ++n)
                    acc[m][n] = __builtin_amdgcn_mfma_f32_16x16x32_bf16(af[m], bf[n], acc[m][n], 0, 0, 0);
        }
    }

    const int orow0 = m0 + wrow + (lane >> 4) * 4;
    const int ocol0 = n0 + wcol + lr;
#pragma unroll
    for (int m = 0; m < MF; ++m)
#pragma unroll
        for (int n = 0; n < NF; ++n) {
            if (OUTMODE == 2) {
                const int nc = ocol0 + n * 16;
                const int mrow = orow0 + m * 16;
                unsigned short* dst = (unsigned short*)Cout
                    + (size_t)((mrow >> 11) * 16 + (nc >> 6)) * (64 * 2048)
                    + (size_t)(nc & 63) * 2048 + (mrow & 2047);
                ushort4v pv;
#pragma unroll
                for (int i = 0; i < 4; ++i) pv[i] = f2b(acc[m][n][i]);
                *(ushort4v*)dst = pv;
            } else {
#pragma unroll
                for (int i = 0; i < 4; ++i) {
                    const size_t idx = (size_t)(orow0 + m * 16 + i) * N + ocol0 + n * 16;
                    if (OUTMODE == 1) ((unsigned short*)Cout)[idx] = f2b(acc[m][n][i]);
                    else              ((float*)Cout)[idx] = acc[m][n][i];
                }
            }
        }
}

// ------------- split-bf16 GEMM (qk projection): ~fp32 via hi/lo, BM=64 -------------
__global__ __launch_bounds__(256) void gemm_split(const unsigned short* __restrict__ Ah,
                                                  const unsigned short* __restrict__ Al,
                                                  const unsigned short* __restrict__ Wh,
                                                  const unsigned short* __restrict__ Wl,
                                                  float* __restrict__ C,
                                                  int M, int N, int K) {
    constexpr int BM = 64, BN = 64, BK = 64;
    constexpr int MF = 2, NF = 2;
    __shared__ __align__(16) unsigned short Ahs[BM * BK];
    __shared__ __align__(16) unsigned short Als[BM * BK];
    __shared__ __align__(16) unsigned short Bhs[BN * BK];
    __shared__ __align__(16) unsigned short Bls[BN * BK];

    const int t = threadIdx.x;
    const int wid = t >> 6, lane = t & 63;
    const int m0 = blockIdx.x * BM, n0 = blockIdx.y * BN;
    const int wrow = (wid >> 1) * 32;
    const int wcol = (wid & 1) * 32;
    const int lr = lane & 15, lk = (lane >> 4) * 8;

    f32x4 acc[MF][NF];
#pragma unroll
    for (int m = 0; m < MF; ++m)
#pragma unroll
        for (int n = 0; n < NF; ++n) acc[m][n] = (f32x4){0.f, 0.f, 0.f, 0.f};

    const unsigned short* Ahg = Ah + (size_t)m0 * K;
    const unsigned short* Alg = Al + (size_t)m0 * K;
    const unsigned short* Whg = Wh + (size_t)n0 * K;
    const unsigned short* Wlg = Wl + (size_t)n0 * K;

    for (int k0 = 0; k0 < K; k0 += BK) {
        __syncthreads();
#pragma unroll
        for (int i = 0; i < BM / 32; ++i) {
            const int e = (i * 256 + wid * 64 + lane) * 8;
            const size_t go = (size_t)(e >> 6) * K + k0 + (e & 63);
            const size_t lo = (size_t)(i * 256 + wid * 64) * 8;
            gload_lds16(Ahg + go, Ahs + lo);
            gload_lds16(Alg + go, Als + lo);
            gload_lds16(Whg + go, Bhs + lo);
            gload_lds16(Wlg + go, Bls + lo);
        }
        __syncthreads();

#pragma unroll
        for (int kk = 0; kk < BK; kk += 32) {
            bf16x8 afh[MF], afl[MF], bfh[NF], bfl[NF];
#pragma unroll
            for (int m = 0; m < MF; ++m) {
                afh[m] = *(const bf16x8*)&Ahs[(wrow + m * 16 + lr) * BK + kk + lk];
                afl[m] = *(const bf16x8*)&Als[(wrow + m * 16 + lr) * BK + kk + lk];
            }
#pragma unroll
            for (int n = 0; n < NF; ++n) {
                bfh[n] = *(const bf16x8*)&Bhs[(wcol + n * 16 + lr) * BK + kk + lk];
                bfl[n] = *(const bf16x8*)&Bls[(wcol + n * 16 + lr) * BK + kk + lk];
            }
#pragma unroll
            for (int m = 0; m < MF; ++m)
#pragma unroll
                for (int n = 0; n < NF; ++n) {
                    acc[m][n] = __builtin_amdgcn_mfma_f32_16x16x32_bf16(afh[m], bfh[n], acc[m][n], 0, 0, 0);
                    acc[m][n] = __builtin_amdgcn_mfma_f32_16x16x32_bf16(afh[m], bfl[n], acc[m][n], 0, 0, 0);
                    acc[m][n] = __builtin_amdgcn_mfma_f32_16x16x32_bf16(afl[m], bfh[n], acc[m][n], 0, 0, 0);
                }
        }
    }

    const int orow0 = m0 + wrow + (lane >> 4) * 4;
    const int ocol0 = n0 + wcol + lr;
#pragma unroll
    for (int m = 0; m < MF; ++m)
#pragma unroll
        for (int n = 0; n < NF; ++n)
#pragma unroll
            for (int i = 0; i < 4; ++i)
                C[(size_t)(orow0 + m * 16 + i) * N + ocol0 + n * 16] = acc[m][n][i];
}

// ---------------- f32 -> bf16 casts ----------------
__global__ __launch_bounds__(256) void cast_bf16(const float* __restrict__ in,
                                                 unsigned short* __restrict__ out, int n) {
    const int i = (blockIdx.x * 256 + threadIdx.x) * 8;
    if (i >= n) return;
    float4 a = *(const float4*)(in + i);
    float4 b = *(const float4*)(in + i + 4);
    ushort8 o;
    o[0] = f2b(a.x); o[1] = f2b(a.y); o[2] = f2b(a.z); o[3] = f2b(a.w);
    o[4] = f2b(b.x); o[5] = f2b(b.y); o[6] = f2b(b.z); o[7] = f2b(b.w);
    *(ushort8*)(out + i) = o;
}

__global__ __launch_bounds__(256) void cast_split(const float* __restrict__ in,
                                                  unsigned short* __restrict__ hi,
                                                  unsigned short* __restrict__ lo, int n) {
    const int i = (blockIdx.x * 256 + threadIdx.x) * 8;
    if (i >= n) return;
    float4 a = *(const float4*)(in + i);
    float4 b = *(const float4*)(in + i + 4);
    float xv[8] = {a.x, a.y, a.z, a.w, b.x, b.y, b.z, b.w};
    ushort8 oh, ol;
#pragma unroll
    for (int e = 0; e < 8; ++e) {
        const unsigned short h = f2b(xv[e]);
        oh[e] = h;
        ol[e] = f2b(xv[e] - b2f(h));
    }
    *(ushort8*)(hi + i) = oh;
    *(ushort8*)(lo + i) = ol;
}

// ------- feature map: qk_raw f32 -> q/k split hi|lo bf16 [bh][l][32] -------
__global__ __launch_bounds__(256) void ln_featuremap(const float* __restrict__ qk,
                                                     const float* __restrict__ gamma,
                                                     const float* __restrict__ beta,
                                                     unsigned short* __restrict__ qhl,
                                                     unsigned short* __restrict__ khl) {
    const int gid = blockIdx.x * 256 + threadIdx.x;
    const int idx = gid & 31;
    const int m = gid >> 5;
    const int b = m >> 11, l = m & 2047;
    const int h = idx & 15;
    const float scale = (idx < 16) ? 0.25f : 1.0f;
    const float* p = qk + (size_t)gid * 16;

    float xv[16];
    float4 v0 = *(const float4*)(p + 0);
    float4 v1 = *(const float4*)(p + 4);
    float4 v2 = *(const float4*)(p + 8);
    float4 v3 = *(const float4*)(p + 12);
    xv[0]=v0.x; xv[1]=v0.y; xv[2]=v0.z; xv[3]=v0.w;
    xv[4]=v1.x; xv[5]=v1.y; xv[6]=v1.z; xv[7]=v1.w;
    xv[8]=v2.x; xv[9]=v2.y; xv[10]=v2.z; xv[11]=v2.w;
    xv[12]=v3.x; xv[13]=v3.y; xv[14]=v3.z; xv[15]=v3.w;

    float mu = 0.f;
#pragma unroll
    for (int f = 0; f < 16; ++f) mu += xv[f];
    mu *= 0.0625f;
    float var = 0.f;
#pragma unroll
    for (int f = 0; f < 16; ++f) { float d = xv[f] - mu; var = fmaf(d, d, var); }
    var *= 0.0625f;
    const float rs = rsqrtf(var + 1e-5f);

    ushort8 hi0, hi1, lo0, lo1;
#pragma unroll
    for (int f = 0; f < 16; ++f) {
        const float v = ((xv[f] - mu) * rs * gamma[f] + beta[f]) * scale;
        const unsigned short hb = f2b(v);
        const unsigned short lb = f2b(v - b2f(hb));
        if (f < 8) { hi0[f] = hb; lo0[f] = lb; }
        else       { hi1[f - 8] = hb; lo1[f - 8] = lb; }
    }
    unsigned short* dst = ((idx < 16) ? qhl : khl)
        + ((size_t)(b * 16 + h) * 2048 + l) * 32;
    *(ushort8*)(dst + 0)  = hi0;
    *(ushort8*)(dst + 8)  = hi1;
    *(ushort8*)(dst + 16) = lo0;
    *(ushort8*)(dst + 24) = lo1;
}

// ------- causal (q.k)^2 attention: full MFMA, triple-buffered 2-ahead staging -------
// grid (32, 32): x = q-tile, y = bh. qhl/khl: [bh][l][32]=[hi16|lo16]; vT: [bh][64][2048].
__global__ __launch_bounds__(256) void rebased_attn(const unsigned short* __restrict__ qhl_g,
                                                    const unsigned short* __restrict__ khl_g,
                                                    const unsigned short* __restrict__ vT,
                                                    unsigned short* __restrict__ o) {
    const int bh = blockIdx.y;
    const int bb = bh >> 4;
    const int t = threadIdx.x;
    const int wid = t >> 6, lane = t & 63;
    const int fr = lane & 15;
    const int fg = lane >> 4;
    const int qt = blockIdx.x;
    const int qbase = qt << 6;

    __shared__ __align__(16) unsigned short khl[3][4 * 64 * 8];   // 3 x 4KB
    __shared__ __align__(16) unsigned short vsl[3][8 * 64 * 8];   // 3 x 8KB
    __shared__ __align__(16) __bf16 P[64][72];                    // 9KB

    const unsigned short* qg  = qhl_g + (size_t)bh * 2048 * 32;
    const unsigned short* kg  = khl_g + (size_t)bh * 2048 * 32;
    const unsigned short* vbh = vT + (size_t)bh * 64 * 2048;
    unsigned short*       obh = o  + (size_t)bb * 2048 * 1024 + (bh & 15) * 64;

    const bf16x8 z8 = {(__bf16)0.f,(__bf16)0.f,(__bf16)0.f,(__bf16)0.f,
                       (__bf16)0.f,(__bf16)0.f,(__bf16)0.f,(__bf16)0.f};
    const f32x4 zc = (f32x4){0.f, 0.f, 0.f, 0.f};

    // Q B-fragments straight from global (per-lane, once per block):
    // row = qbase + 16*wid + fr, octets (fg&1) [hi] and (fg&1)+2 [lo]
    const unsigned short* qrow = qg + (size_t)(qbase + 16 * wid + fr) * 32;
    const bf16x8 bq1 = *(const bf16x8*)&qrow[(fg & 1) * 8];
    const bf16x8 bq2 = *(const bf16x8*)&qrow[((fg & 1) + 2) * 8];

#define STAGE_KV(kt_, buf_)                                                          \
    do {                                                                             \
        gload_lds16(kg + ((size_t)((kt_) << 6) + lane) * 32 + wid * 8,               \
                    &khl[buf_][wid * 512]);                                          \
        gload_lds16(vbh + (size_t)lane * 2048 + ((kt_) << 6) + (2 * wid) * 8,        \
                    &vsl[buf_][(2 * wid) * 512]);                                    \
        gload_lds16(vbh + (size_t)lane * 2048 + ((kt_) << 6) + (2 * wid + 1) * 8,    \
                    &vsl[buf_][(2 * wid + 1) * 512]);                                \
    } while (0)

    // prologue: stage kt=0 (+ kt=1), drain once, sync
    STAGE_KV(0, 0);
    if (qt >= 1) STAGE_KV(1, 1);
    asm volatile("s_waitcnt vmcnt(0)" ::: "memory");
    __syncthreads();

    f32x4 oacc[4];
#pragma unroll
    for (int n = 0; n < 4; ++n) oacc[n] = zc;
    float zlane = 0.f;

    for (int kt = 0; kt <= qt; ++kt) {
        const int cur = kt % 3;
        // prefetch 2 ahead into buffer freed at step kt-1's barrier
        if (kt + 2 <= qt) STAGE_KV(kt + 2, (kt + 2) % 3);

        // phase 1: S^T strip = K(all 64) x Q(wave's 16), hi/lo MFMA pair
#pragma unroll
        for (int nrow = 0; nrow < 4; ++nrow) {
            const bf16x8 ak  = *(const bf16x8*)&khl[cur][(fg * 64 + nrow * 16 + fr) * 8];
            const bf16x8 ak2 = (fg < 2) ? ak : z8;           // [kh|0]
            f32x4 s = __builtin_amdgcn_mfma_f32_16x16x32_bf16(ak2, bq2, zc, 0, 0, 0);
            s = __builtin_amdgcn_mfma_f32_16x16x32_bf16(ak, bq1, s, 0, 0, 0);

            float s2[4];
            if (kt == qt) {
                const int qr = 16 * wid + fr;
                const int kc = nrow * 16 + fg * 4;
#pragma unroll
                for (int reg = 0; reg < 4; ++reg) {
                    float x = s[reg];
                    float y = x * x;
                    s2[reg] = (kc + reg <= qr) ? y : 0.f;
                    zlane += s2[reg];
                }
            } else {
#pragma unroll
                for (int reg = 0; reg < 4; ++reg) {
                    float x = s[reg];
                    s2[reg] = x * x;
                    zlane += s2[reg];
                }
            }
            bf16x4 pv = {(__bf16)s2[0], (__bf16)s2[1], (__bf16)s2[2], (__bf16)s2[3]};
            *(bf16x4*)&P[16 * wid + fr][nrow * 16 + fg * 4] = pv;
        }

        // phase 2: O strip += P_strip @ V (same-wave P)
        const bf16x8 a0 = *(const bf16x8*)&P[16 * wid + fr][fg * 8];
        const bf16x8 a1 = *(const bf16x8*)&P[16 * wid + fr][32 + fg * 8];
#pragma unroll
        for (int nt = 0; nt < 4; ++nt) {
            const bf16x8 b0 = *(const bf16x8*)&vsl[cur][((fg    ) * 64 + nt * 16 + fr) * 8];
            const bf16x8 b1 = *(const bf16x8*)&vsl[cur][((fg + 4) * 64 + nt * 16 + fr) * 8];
            oacc[nt] = __builtin_amdgcn_mfma_f32_16x16x32_bf16(a0, b0, oacc[nt], 0, 0, 0);
            oacc[nt] = __builtin_amdgcn_mfma_f32_16x16x32_bf16(a1, b1, oacc[nt], 0, 0, 0);
        }

        // counted wait: next tile (kt+1) must be resident; kt+2's 3 loads may fly
        if (kt + 2 <= qt) asm volatile("s_waitcnt vmcnt(3)" ::: "memory");
        else              asm volatile("s_waitcnt vmcnt(0)" ::: "memory");
        __builtin_amdgcn_s_barrier();
        __builtin_amdgcn_sched_barrier(0);
    }
#undef STAGE_KV

    // z: lane groups {fr, fr+16, fr+32, fr+48} share q=16*wid+fr
    float z = zlane;
    z += __shfl_xor(z, 16);
    z += __shfl_xor(z, 32);
    const float zinv = 1.f / (z + 1e-5f);

    // epilogue: oacc D-layout row = fg*4+reg (q), col = fr (d within nt)
#pragma unroll
    for (int reg = 0; reg < 4; ++reg) {
        const float r = __shfl(zinv, fg * 4 + reg);
        const size_t gro = (size_t)(qbase + 16 * wid + fg * 4 + reg) * 1024;
#pragma unroll
        for (int nt = 0; nt < 4; ++nt)
            obh[gro + nt * 16 + fr] = f2b(oacc[nt][reg] * r);
    }
}

extern "C" void kernel_launch(void* const* d_in, const int* in_sizes, int n_in,
                              void* d_out, int out_size, void* d_ws, size_t ws_size,
                              hipStream_t stream) {
    const float* x     = (const float*)d_in[0];
    const float* Wq    = (const float*)d_in[1];
    const float* Wk    = (const float*)d_in[2];
    const float* Wv    = (const float*)d_in[3];
    const float* Wo    = (const float*)d_in[4];
    const float* gamma = (const float*)d_in[5];
    const float* beta  = (const float*)d_in[6];
    float* out = (float*)d_out;
    (void)in_sizes; (void)n_in; (void)out_size; (void)ws_size;

    char* w = (char*)d_ws;
    float*          qk_raw = (float*)w;                                   // 8 MB @ 0
    unsigned short* vTb    = (unsigned short*)(w + (8u  << 20));          // 8 MB [bh][64][2048]
    unsigned short* ob     = (unsigned short*)(w + (16u << 20));          // 8 MB
    unsigned short* xh     = (unsigned short*)(w + (24u << 20));          // 8 MB (dead after gemms)
    unsigned short* xl     = (unsigned short*)(w + (32u << 20));          // 8 MB (dead after gemm_split)
    unsigned short* qhl_g  = (unsigned short*)(w + (24u << 20));          // 4 MB (overlays dead xh)
    unsigned short* khl_g  = (unsigned short*)(w + (28u << 20));          // 4 MB (overlays dead xh)
    unsigned short* wqkh   = (unsigned short*)(w + (40u << 20));          // 1 MB
    unsigned short* wqkl   = (unsigned short*)(w + (41u << 20));          // 1 MB
    unsigned short* wvb    = (unsigned short*)(w + (42u << 20));          // 2 MB
    unsigned short* wob    = (unsigned short*)(w + (44u << 20));          // 2 MB

    cast_split<<<2048, 256, 0, stream>>>(x,  xh, xl, 4096 * 1024);
    cast_split<<<128,  256, 0, stream>>>(Wq, wqkh, wqkl, 256 * 1024);
    cast_split<<<128,  256, 0, stream>>>(Wk, wqkh + 256 * 1024, wqkl + 256 * 1024, 256 * 1024);
    cast_bf16 <<<512,  256, 0, stream>>>(Wv, wvb, 1024 * 1024);
    cast_bf16 <<<512,  256, 0, stream>>>(Wo, wob, 1024 * 1024);

    // qk projection (split-bf16, ~fp32): [4096][512] f32
    gemm_split<<<dim3(64, 8), 256, 0, stream>>>(xh, xl, wqkh, wqkl, qk_raw, 4096, 512, 1024);
    // v projection -> transposed bf16 vT[bh][d][l], BN=64 -> grid 1024 (4 blocks/CU)
    gemm_mfma<64, 64, 2><<<dim3(64, 16), 256, 0, stream>>>(xh, wvb, vTb, 4096, 1024, 1024);
    // feature map -> q/k hi|lo bf16 [bh][l][32]
    ln_featuremap<<<512, 256, 0, stream>>>(qk_raw, gamma, beta, qhl_g, khl_g);
    // attention -> bf16 ob (b, l, h*64+d); unpaired q-tiles, grid 1024
    rebased_attn<<<dim3(32, 32), 256, 0, stream>>>(qhl_g, khl_g, vTb, ob);
    // output projection -> f32 out, BN=64 -> grid 1024
    gemm_mfma<64, 64, 0><<<dim3(64, 16), 256, 0, stream>>>(ob, wob, out, 4096, 1024, 1024);
}

// Round 9
// 125.646 us; speedup vs baseline: 1.2988x; 1.2988x over previous
//
#include <hip/hip_runtime.h>
#include <cstddef>
#include <cstdint>

// ReBased linear attention, round 9.
// r8 post-mortem: unpaired q-tiles = load imbalance (blocks do 1..32 steps);
// makespan set by unlucky CUs -> 2x regression. Fix: QUAD blocks. One
// 1024-thread block = 4 wave-groups x 4 waves, handling q-tiles
// {x, 15-x, 16+x, 31-x} of ONE (b,h) -- all four share the SAME K/V stream
// (staged once per step). grid (8,32)=256 blocks = exactly 1/CU, 16 waves/CU,
// deterministic balance (25..32 steps). K/V staged bytes drop 2.3x.

typedef __attribute__((ext_vector_type(8)))  __bf16 bf16x8;
typedef __attribute__((ext_vector_type(4)))  __bf16 bf16x4;
typedef __attribute__((ext_vector_type(4)))  float  f32x4;
typedef __attribute__((ext_vector_type(8)))  unsigned short ushort8;
typedef __attribute__((ext_vector_type(4)))  unsigned short ushort4v;

__device__ __forceinline__ unsigned short f2b(float f) {
    union { float f; unsigned u; } v; v.f = f;
    unsigned r = v.u + 0x7FFFu + ((v.u >> 16) & 1u);   // RNE
    return (unsigned short)(r >> 16);
}
__device__ __forceinline__ float b2f(unsigned short b) {
    union { unsigned u; float f; } v; v.u = ((unsigned)b) << 16;
    return v.f;
}

typedef const __attribute__((address_space(1))) void* gas_ptr;
typedef __attribute__((address_space(3))) void* las_ptr;

__device__ __forceinline__ void gload_lds16(const unsigned short* g, unsigned short* l) {
    // 16B/lane; LDS dest = wave-uniform base + lane*16
    __builtin_amdgcn_global_load_lds((gas_ptr)g, (las_ptr)l, 16, 0, 0);
}

// ---------------- bf16 MFMA GEMM: C[M][N] = A[M][K] @ W[N][K]^T ----------------
// 256 threads = 4 waves (2x2). OUTMODE: 0=f32, 1=bf16, 2=bf16 vT scatter.
template <int BM, int BN, int OUTMODE>
__global__ __launch_bounds__(256) void gemm_mfma(const unsigned short* __restrict__ A,
                                                 const unsigned short* __restrict__ W,
                                                 void* __restrict__ Cout,
                                                 int M, int N, int K) {
    constexpr int BK = 64;
    constexpr int MF = BM / 32;
    constexpr int NF = BN / 32;
    __shared__ __align__(16) unsigned short As[BM * BK];
    __shared__ __align__(16) unsigned short Bs[BN * BK];

    const int t = threadIdx.x;
    const int wid = t >> 6, lane = t & 63;
    const int m0 = blockIdx.x * BM, n0 = blockIdx.y * BN;
    const int wrow = (wid >> 1) * (BM / 2);
    const int wcol = (wid & 1) * (BN / 2);
    const int lr = lane & 15, lk = (lane >> 4) * 8;

    f32x4 acc[MF][NF];
#pragma unroll
    for (int m = 0; m < MF; ++m)
#pragma unroll
        for (int n = 0; n < NF; ++n) acc[m][n] = (f32x4){0.f, 0.f, 0.f, 0.f};

    const unsigned short* Ag = A + (size_t)m0 * K;
    const unsigned short* Wg = W + (size_t)n0 * K;

    for (int k0 = 0; k0 < K; k0 += BK) {
        __syncthreads();
#pragma unroll
        for (int i = 0; i < BM / 32; ++i) {
            const int e = (i * 256 + wid * 64 + lane) * 8;
            gload_lds16(Ag + (size_t)(e >> 6) * K + k0 + (e & 63),
                        As + (size_t)(i * 256 + wid * 64) * 8);
        }
#pragma unroll
        for (int i = 0; i < BN / 32; ++i) {
            const int e = (i * 256 + wid * 64 + lane) * 8;
            gload_lds16(Wg + (size_t)(e >> 6) * K + k0 + (e & 63),
                        Bs + (size_t)(i * 256 + wid * 64) * 8);
        }
        __syncthreads();

#pragma unroll
        for (int kk = 0; kk < BK; kk += 32) {
            bf16x8 af[MF], bf[NF];
#pragma unroll
            for (int m = 0; m < MF; ++m)
                af[m] = *(const bf16x8*)&As[(wrow + m * 16 + lr) * BK + kk + lk];
#pragma unroll
            for (int n = 0; n < NF; ++n)
                bf[n] = *(const bf16x8*)&Bs[(wcol + n * 16 + lr) * BK + kk + lk];
#pragma unroll
            for (int m = 0; m < MF; ++m)
#pragma unroll
                for (int n = 0; n < NF; ++n)
                    acc[m][n] = __builtin_amdgcn_mfma_f32_16x16x32_bf16(af[m], bf[n], acc[m][n], 0, 0, 0);
        }
    }

    const int orow0 = m0 + wrow + (lane >> 4) * 4;
    const int ocol0 = n0 + wcol + lr;
#pragma unroll
    for (int m = 0; m < MF; ++m)
#pragma unroll
        for (int n = 0; n < NF; ++n) {
            if (OUTMODE == 2) {
                const int nc = ocol0 + n * 16;
                const int mrow = orow0 + m * 16;
                unsigned short* dst = (unsigned short*)Cout
                    + (size_t)((mrow >> 11) * 16 + (nc >> 6)) * (64 * 2048)
                    + (size_t)(nc & 63) * 2048 + (mrow & 2047);
                ushort4v pv;
#pragma unroll
                for (int i = 0; i < 4; ++i) pv[i] = f2b(acc[m][n][i]);
                *(ushort4v*)dst = pv;
            } else {
#pragma unroll
                for (int i = 0; i < 4; ++i) {
                    const size_t idx = (size_t)(orow0 + m * 16 + i) * N + ocol0 + n * 16;
                    if (OUTMODE == 1) ((unsigned short*)Cout)[idx] = f2b(acc[m][n][i]);
                    else              ((float*)Cout)[idx] = acc[m][n][i];
                }
            }
        }
}

// ------------- split-bf16 GEMM (qk projection): ~fp32 via hi/lo, BM=64 -------------
__global__ __launch_bounds__(256) void gemm_split(const unsigned short* __restrict__ Ah,
                                                  const unsigned short* __restrict__ Al,
                                                  const unsigned short* __restrict__ Wh,
                                                  const unsigned short* __restrict__ Wl,
                                                  float* __restrict__ C,
                                                  int M, int N, int K) {
    constexpr int BM = 64, BN = 64, BK = 64;
    constexpr int MF = 2, NF = 2;
    __shared__ __align__(16) unsigned short Ahs[BM * BK];
    __shared__ __align__(16) unsigned short Als[BM * BK];
    __shared__ __align__(16) unsigned short Bhs[BN * BK];
    __shared__ __align__(16) unsigned short Bls[BN * BK];

    const int t = threadIdx.x;
    const int wid = t >> 6, lane = t & 63;
    const int m0 = blockIdx.x * BM, n0 = blockIdx.y * BN;
    const int wrow = (wid >> 1) * 32;
    const int wcol = (wid & 1) * 32;
    const int lr = lane & 15, lk = (lane >> 4) * 8;

    f32x4 acc[MF][NF];
#pragma unroll
    for (int m = 0; m < MF; ++m)
#pragma unroll
        for (int n = 0; n < NF; ++n) acc[m][n] = (f32x4){0.f, 0.f, 0.f, 0.f};

    const unsigned short* Ahg = Ah + (size_t)m0 * K;
    const unsigned short* Alg = Al + (size_t)m0 * K;
    const unsigned short* Whg = Wh + (size_t)n0 * K;
    const unsigned short* Wlg = Wl + (size_t)n0 * K;

    for (int k0 = 0; k0 < K; k0 += BK) {
        __syncthreads();
#pragma unroll
        for (int i = 0; i < BM / 32; ++i) {
            const int e = (i * 256 + wid * 64 + lane) * 8;
            const size_t go = (size_t)(e >> 6) * K + k0 + (e & 63);
            const size_t lo = (size_t)(i * 256 + wid * 64) * 8;
            gload_lds16(Ahg + go, Ahs + lo);
            gload_lds16(Alg + go, Als + lo);
            gload_lds16(Whg + go, Bhs + lo);
            gload_lds16(Wlg + go, Bls + lo);
        }
        __syncthreads();

#pragma unroll
        for (int kk = 0; kk < BK; kk += 32) {
            bf16x8 afh[MF], afl[MF], bfh[NF], bfl[NF];
#pragma unroll
            for (int m = 0; m < MF; ++m) {
                afh[m] = *(const bf16x8*)&Ahs[(wrow + m * 16 + lr) * BK + kk + lk];
                afl[m] = *(const bf16x8*)&Als[(wrow + m * 16 + lr) * BK + kk + lk];
            }
#pragma unroll
            for (int n = 0; n < NF; ++n) {
                bfh[n] = *(const bf16x8*)&Bhs[(wcol + n * 16 + lr) * BK + kk + lk];
                bfl[n] = *(const bf16x8*)&Bls[(wcol + n * 16 + lr) * BK + kk + lk];
            }
#pragma unroll
            for (int m = 0; m < MF; ++m)
#pragma unroll
                for (int n = 0; n < NF; ++n) {
                    acc[m][n] = __builtin_amdgcn_mfma_f32_16x16x32_bf16(afh[m], bfh[n], acc[m][n], 0, 0, 0);
                    acc[m][n] = __builtin_amdgcn_mfma_f32_16x16x32_bf16(afh[m], bfl[n], acc[m][n], 0, 0, 0);
                    acc[m][n] = __builtin_amdgcn_mfma_f32_16x16x32_bf16(afl[m], bfh[n], acc[m][n], 0, 0, 0);
                }
        }
    }

    const int orow0 = m0 + wrow + (lane >> 4) * 4;
    const int ocol0 = n0 + wcol + lr;
#pragma unroll
    for (int m = 0; m < MF; ++m)
#pragma unroll
        for (int n = 0; n < NF; ++n)
#pragma unroll
            for (int i = 0; i < 4; ++i)
                C[(size_t)(orow0 + m * 16 + i) * N + ocol0 + n * 16] = acc[m][n][i];
}

// ---------------- f32 -> bf16 casts ----------------
__global__ __launch_bounds__(256) void cast_bf16(const float* __restrict__ in,
                                                 unsigned short* __restrict__ out, int n) {
    const int i = (blockIdx.x * 256 + threadIdx.x) * 8;
    if (i >= n) return;
    float4 a = *(const float4*)(in + i);
    float4 b = *(const float4*)(in + i + 4);
    ushort8 o;
    o[0] = f2b(a.x); o[1] = f2b(a.y); o[2] = f2b(a.z); o[3] = f2b(a.w);
    o[4] = f2b(b.x); o[5] = f2b(b.y); o[6] = f2b(b.z); o[7] = f2b(b.w);
    *(ushort8*)(out + i) = o;
}

__global__ __launch_bounds__(256) void cast_split(const float* __restrict__ in,
                                                  unsigned short* __restrict__ hi,
                                                  unsigned short* __restrict__ lo, int n) {
    const int i = (blockIdx.x * 256 + threadIdx.x) * 8;
    if (i >= n) return;
    float4 a = *(const float4*)(in + i);
    float4 b = *(const float4*)(in + i + 4);
    float xv[8] = {a.x, a.y, a.z, a.w, b.x, b.y, b.z, b.w};
    ushort8 oh, ol;
#pragma unroll
    for (int e = 0; e < 8; ++e) {
        const unsigned short h = f2b(xv[e]);
        oh[e] = h;
        ol[e] = f2b(xv[e] - b2f(h));
    }
    *(ushort8*)(hi + i) = oh;
    *(ushort8*)(lo + i) = ol;
}

// ------- feature map: qk_raw f32 -> q/k split hi|lo bf16 [bh][l][32] -------
__global__ __launch_bounds__(256) void ln_featuremap(const float* __restrict__ qk,
                                                     const float* __restrict__ gamma,
                                                     const float* __restrict__ beta,
                                                     unsigned short* __restrict__ qhl,
                                                     unsigned short* __restrict__ khl) {
    const int gid = blockIdx.x * 256 + threadIdx.x;
    const int idx = gid & 31;
    const int m = gid >> 5;
    const int b = m >> 11, l = m & 2047;
    const int h = idx & 15;
    const float scale = (idx < 16) ? 0.25f : 1.0f;
    const float* p = qk + (size_t)gid * 16;

    float xv[16];
    float4 v0 = *(const float4*)(p + 0);
    float4 v1 = *(const float4*)(p + 4);
    float4 v2 = *(const float4*)(p + 8);
    float4 v3 = *(const float4*)(p + 12);
    xv[0]=v0.x; xv[1]=v0.y; xv[2]=v0.z; xv[3]=v0.w;
    xv[4]=v1.x; xv[5]=v1.y; xv[6]=v1.z; xv[7]=v1.w;
    xv[8]=v2.x; xv[9]=v2.y; xv[10]=v2.z; xv[11]=v2.w;
    xv[12]=v3.x; xv[13]=v3.y; xv[14]=v3.z; xv[15]=v3.w;

    float mu = 0.f;
#pragma unroll
    for (int f = 0; f < 16; ++f) mu += xv[f];
    mu *= 0.0625f;
    float var = 0.f;
#pragma unroll
    for (int f = 0; f < 16; ++f) { float d = xv[f] - mu; var = fmaf(d, d, var); }
    var *= 0.0625f;
    const float rs = rsqrtf(var + 1e-5f);

    ushort8 hi0, hi1, lo0, lo1;
#pragma unroll
    for (int f = 0; f < 16; ++f) {
        const float v = ((xv[f] - mu) * rs * gamma[f] + beta[f]) * scale;
        const unsigned short hb = f2b(v);
        const unsigned short lb = f2b(v - b2f(hb));
        if (f < 8) { hi0[f] = hb; lo0[f] = lb; }
        else       { hi1[f - 8] = hb; lo1[f - 8] = lb; }
    }
    unsigned short* dst = ((idx < 16) ? qhl : khl)
        + ((size_t)(b * 16 + h) * 2048 + l) * 32;
    *(ushort8*)(dst + 0)  = hi0;
    *(ushort8*)(dst + 8)  = hi1;
    *(ushort8*)(dst + 16) = lo0;
    *(ushort8*)(dst + 24) = lo1;
}

// ------- causal (q.k)^2 attention: quad-tile blocks, shared K/V stream -------
// grid (8, 32): x -> q-tiles {x, 15-x, 16+x, 31-x} of bh = blockIdx.y.
// 1024 threads = 4 groups x 4 waves; group g owns one q-tile.
// qhl/khl: [bh][l][32]=[hi16|lo16]; vT: [bh][64 d][2048 l].
__global__ __launch_bounds__(1024) void rebased_attn(const unsigned short* __restrict__ qhl_g,
                                                     const unsigned short* __restrict__ khl_g,
                                                     const unsigned short* __restrict__ vT,
                                                     unsigned short* __restrict__ o) {
    const int bh = blockIdx.y;
    const int bb = bh >> 4;
    const int t = threadIdx.x;
    const int wid = t >> 6, lane = t & 63;
    const int g = wid >> 2, lw = wid & 3;   // group, wave-in-group
    const int fr = lane & 15;
    const int fg = lane >> 4;
    const int x = blockIdx.x;               // 0..7
    const int qt = (g == 0) ? x : (g == 1) ? (15 - x) : (g == 2) ? (16 + x) : (31 - x);
    const int qtmax = 31 - x;               // group 3 is always longest
    const int qbase = qt << 6;

    __shared__ __align__(16) unsigned short khl[2][4 * 64 * 8];   // 2 x 4KB
    __shared__ __align__(16) unsigned short vsl[2][8 * 64 * 8];   // 2 x 8KB
    __shared__ __align__(16) __bf16 P[256][72];                   // 36KB (per-wave rows)

    const unsigned short* qg  = qhl_g + (size_t)bh * 2048 * 32;
    const unsigned short* kg  = khl_g + (size_t)bh * 2048 * 32;
    const unsigned short* vbh = vT + (size_t)bh * 64 * 2048;
    unsigned short*       obh = o  + (size_t)bb * 2048 * 1024 + (bh & 15) * 64;

    const bf16x8 z8 = {(__bf16)0.f,(__bf16)0.f,(__bf16)0.f,(__bf16)0.f,
                       (__bf16)0.f,(__bf16)0.f,(__bf16)0.f,(__bf16)0.f};
    const f32x4 zc = (f32x4){0.f, 0.f, 0.f, 0.f};

    // Q B-fragments straight from global (per-lane, once):
    const unsigned short* qrow = qg + (size_t)(qbase + 16 * lw + fr) * 32;
    const bf16x8 bq1 = *(const bf16x8*)&qrow[(fg & 1) * 8];
    const bf16x8 bq2 = *(const bf16x8*)&qrow[((fg & 1) + 2) * 8];

    // staging: 12 chunks (K:4 + V:8) over waves 0..11, 1 load-inst/wave
#define STAGE_KV(kt_, buf_)                                                           \
    do {                                                                              \
        if (wid < 4)                                                                  \
            gload_lds16(kg + ((size_t)((kt_) << 6) + lane) * 32 + wid * 8,            \
                        &khl[buf_][wid * 512]);                                       \
        else if (wid < 12)                                                            \
            gload_lds16(vbh + (size_t)lane * 2048 + ((kt_) << 6) + (wid - 4) * 8,     \
                        &vsl[buf_][(wid - 4) * 512]);                                 \
    } while (0)

    STAGE_KV(0, 0);
    asm volatile("s_waitcnt vmcnt(0)" ::: "memory");
    __syncthreads();

    f32x4 oacc[4];
#pragma unroll
    for (int n = 0; n < 4; ++n) oacc[n] = zc;
    float zlane = 0.f;

    for (int kt = 0; kt <= qtmax; ++kt) {
        const int cur = kt & 1;
        if (kt < qtmax) STAGE_KV(kt + 1, cur ^ 1);   // prefetch overlaps compute

        if (kt <= qt) {   // wave-uniform: group still active
            const int prow = 64 * g + 16 * lw + fr;
            // phase 1: S^T strip = K(all 64) x Q(group's 16 rows owned by wave)
#pragma unroll
            for (int nrow = 0; nrow < 4; ++nrow) {
                const bf16x8 ak  = *(const bf16x8*)&khl[cur][(fg * 64 + nrow * 16 + fr) * 8];
                const bf16x8 ak2 = (fg < 2) ? ak : z8;           // [kh|0]
                f32x4 s = __builtin_amdgcn_mfma_f32_16x16x32_bf16(ak2, bq2, zc, 0, 0, 0);
                s = __builtin_amdgcn_mfma_f32_16x16x32_bf16(ak, bq1, s, 0, 0, 0);

                float s2[4];
                if (kt == qt) {
                    const int qr = 16 * lw + fr;
                    const int kc = nrow * 16 + fg * 4;
#pragma unroll
                    for (int reg = 0; reg < 4; ++reg) {
                        float xs = s[reg];
                        float y = xs * xs;
                        s2[reg] = (kc + reg <= qr) ? y : 0.f;
                        zlane += s2[reg];
                    }
                } else {
#pragma unroll
                    for (int reg = 0; reg < 4; ++reg) {
                        float xs = s[reg];
                        s2[reg] = xs * xs;
                        zlane += s2[reg];
                    }
                }
                bf16x4 pv = {(__bf16)s2[0], (__bf16)s2[1], (__bf16)s2[2], (__bf16)s2[3]};
                *(bf16x4*)&P[prow][nrow * 16 + fg * 4] = pv;   // wave-private row
            }

            // phase 2: O strip += P_strip @ V (same-wave P, no extra barrier)
            const bf16x8 a0 = *(const bf16x8*)&P[prow][fg * 8];
            const bf16x8 a1 = *(const bf16x8*)&P[prow][32 + fg * 8];
#pragma unroll
            for (int nt = 0; nt < 4; ++nt) {
                const bf16x8 b0 = *(const bf16x8*)&vsl[cur][((fg    ) * 64 + nt * 16 + fr) * 8];
                const bf16x8 b1 = *(const bf16x8*)&vsl[cur][((fg + 4) * 64 + nt * 16 + fr) * 8];
                oacc[nt] = __builtin_amdgcn_mfma_f32_16x16x32_bf16(a0, b0, oacc[nt], 0, 0, 0);
                oacc[nt] = __builtin_amdgcn_mfma_f32_16x16x32_bf16(a1, b1, oacc[nt], 0, 0, 0);
            }
        }

        asm volatile("s_waitcnt vmcnt(0)" ::: "memory");   // own prefetch landed
        __builtin_amdgcn_s_barrier();                       // all staging visible
    }
#undef STAGE_KV

    // z: lanes {fr, fr+16, fr+32, fr+48} share q-row 16*lw+fr
    float z = zlane;
    z += __shfl_xor(z, 16);
    z += __shfl_xor(z, 32);
    const float zinv = 1.f / (z + 1e-5f);

    // epilogue: oacc D-layout row = fg*4+reg (q within 16), col = fr (d within nt)
#pragma unroll
    for (int reg = 0; reg < 4; ++reg) {
        const float r = __shfl(zinv, fg * 4 + reg);
        const size_t gro = (size_t)(qbase + 16 * lw + fg * 4 + reg) * 1024;
#pragma unroll
        for (int nt = 0; nt < 4; ++nt)
            obh[gro + nt * 16 + fr] = f2b(oacc[nt][reg] * r);
    }
}

extern "C" void kernel_launch(void* const* d_in, const int* in_sizes, int n_in,
                              void* d_out, int out_size, void* d_ws, size_t ws_size,
                              hipStream_t stream) {
    const float* x     = (const float*)d_in[0];
    const float* Wq    = (const float*)d_in[1];
    const float* Wk    = (const float*)d_in[2];
    const float* Wv    = (const float*)d_in[3];
    const float* Wo    = (const float*)d_in[4];
    const float* gamma = (const float*)d_in[5];
    const float* beta  = (const float*)d_in[6];
    float* out = (float*)d_out;
    (void)in_sizes; (void)n_in; (void)out_size; (void)ws_size;

    char* w = (char*)d_ws;
    float*          qk_raw = (float*)w;                                   // 8 MB @ 0
    unsigned short* vTb    = (unsigned short*)(w + (8u  << 20));          // 8 MB [bh][64][2048]
    unsigned short* ob     = (unsigned short*)(w + (16u << 20));          // 8 MB
    unsigned short* xh     = (unsigned short*)(w + (24u << 20));          // 8 MB (dead after gemms)
    unsigned short* xl     = (unsigned short*)(w + (32u << 20));          // 8 MB (dead after gemm_split)
    unsigned short* qhl_g  = (unsigned short*)(w + (24u << 20));          // 4 MB (overlays dead xh)
    unsigned short* khl_g  = (unsigned short*)(w + (28u << 20));          // 4 MB (overlays dead xh)
    unsigned short* wqkh   = (unsigned short*)(w + (40u << 20));          // 1 MB
    unsigned short* wqkl   = (unsigned short*)(w + (41u << 20));          // 1 MB
    unsigned short* wvb    = (unsigned short*)(w + (42u << 20));          // 2 MB
    unsigned short* wob    = (unsigned short*)(w + (44u << 20));          // 2 MB

    cast_split<<<2048, 256, 0, stream>>>(x,  xh, xl, 4096 * 1024);
    cast_split<<<128,  256, 0, stream>>>(Wq, wqkh, wqkl, 256 * 1024);
    cast_split<<<128,  256, 0, stream>>>(Wk, wqkh + 256 * 1024, wqkl + 256 * 1024, 256 * 1024);
    cast_bf16 <<<512,  256, 0, stream>>>(Wv, wvb, 1024 * 1024);
    cast_bf16 <<<512,  256, 0, stream>>>(Wo, wob, 1024 * 1024);

    // qk projection (split-bf16, ~fp32): [4096][512] f32
    gemm_split<<<dim3(64, 8), 256, 0, stream>>>(xh, xl, wqkh, wqkl, qk_raw, 4096, 512, 1024);
    // v projection -> transposed bf16 vT[bh][d][l]
    gemm_mfma<64, 64, 2><<<dim3(64, 16), 256, 0, stream>>>(xh, wvb, vTb, 4096, 1024, 1024);
    // feature map -> q/k hi|lo bf16 [bh][l][32]
    ln_featuremap<<<512, 256, 0, stream>>>(qk_raw, gamma, beta, qhl_g, khl_g);
    // attention -> bf16 ob (b, l, h*64+d); quad-tile blocks, grid 256 = 1/CU
    rebased_attn<<<dim3(8, 32), 1024, 0, stream>>>(qhl_g, khl_g, vTb, ob);
    // output projection -> f32 out
    gemm_mfma<64, 64, 0><<<dim3(64, 16), 256, 0, stream>>>(ob, wob, out, 4096, 1024, 1024);
}

// Round 10
// 123.797 us; speedup vs baseline: 1.3182x; 1.0149x over previous
//
#include <hip/hip_runtime.h>
#include <cstddef>
#include <cstdint>

// ReBased linear attention, round 10.
// r9 post-mortem: quad-blocks balanced but grid (8,32) put the 8 blocks sharing
// one (b,h)'s K/V on 8 DIFFERENT XCDs (id%8 = x) -> every block streamed K/V
// from HBM; vmcnt(0) each step paid ~900cy. Fixes:
//  - attn grid (32,8): x=bh -> id%8 = bh%8 -> same-bh blocks colocate on one
//    XCD; K/V L2-resident (1.5MB/XCD). Triple-buffer, 2-ahead prefetch,
//    counted vmcnt(1) (1 staging load per wave per step).
//  - GEMMs: 2-phase double-buffered LDS (stage(k+1) before compute(k); one
//    sync per tile) -- T3 minimum recipe.

typedef __attribute__((ext_vector_type(8)))  __bf16 bf16x8;
typedef __attribute__((ext_vector_type(4)))  __bf16 bf16x4;
typedef __attribute__((ext_vector_type(4)))  float  f32x4;
typedef __attribute__((ext_vector_type(8)))  unsigned short ushort8;
typedef __attribute__((ext_vector_type(4)))  unsigned short ushort4v;

__device__ __forceinline__ unsigned short f2b(float f) {
    union { float f; unsigned u; } v; v.f = f;
    unsigned r = v.u + 0x7FFFu + ((v.u >> 16) & 1u);   // RNE
    return (unsigned short)(r >> 16);
}
__device__ __forceinline__ float b2f(unsigned short b) {
    union { unsigned u; float f; } v; v.u = ((unsigned)b) << 16;
    return v.f;
}

typedef const __attribute__((address_space(1))) void* gas_ptr;
typedef __attribute__((address_space(3))) void* las_ptr;

__device__ __forceinline__ void gload_lds16(const unsigned short* g, unsigned short* l) {
    // 16B/lane; LDS dest = wave-uniform base + lane*16
    __builtin_amdgcn_global_load_lds((gas_ptr)g, (las_ptr)l, 16, 0, 0);
}

// ---------------- bf16 MFMA GEMM, 2-phase dbuf: C = A @ W^T ----------------
// 256 threads = 4 waves (2x2). OUTMODE: 0=f32, 1=bf16, 2=bf16 vT scatter.
template <int BM, int BN, int OUTMODE>
__global__ __launch_bounds__(256) void gemm_mfma(const unsigned short* __restrict__ A,
                                                 const unsigned short* __restrict__ W,
                                                 void* __restrict__ Cout,
                                                 int M, int N, int K) {
    constexpr int BK = 64;
    constexpr int MF = BM / 32;
    constexpr int NF = BN / 32;
    __shared__ __align__(16) unsigned short As[2][BM * BK];
    __shared__ __align__(16) unsigned short Bs[2][BN * BK];

    const int t = threadIdx.x;
    const int wid = t >> 6, lane = t & 63;
    const int m0 = blockIdx.x * BM, n0 = blockIdx.y * BN;
    const int wrow = (wid >> 1) * (BM / 2);
    const int wcol = (wid & 1) * (BN / 2);
    const int lr = lane & 15, lk = (lane >> 4) * 8;

    f32x4 acc[MF][NF];
#pragma unroll
    for (int m = 0; m < MF; ++m)
#pragma unroll
        for (int n = 0; n < NF; ++n) acc[m][n] = (f32x4){0.f, 0.f, 0.f, 0.f};

    const unsigned short* Ag = A + (size_t)m0 * K;
    const unsigned short* Wg = W + (size_t)n0 * K;

#define G_STAGE(k0_, buf_)                                                        \
    do {                                                                          \
        _Pragma("unroll")                                                         \
        for (int i = 0; i < BM / 32; ++i) {                                       \
            const int e = (i * 256 + wid * 64 + lane) * 8;                        \
            gload_lds16(Ag + (size_t)(e >> 6) * K + (k0_) + (e & 63),             \
                        &As[buf_][(size_t)(i * 256 + wid * 64) * 8]);             \
        }                                                                         \
        _Pragma("unroll")                                                         \
        for (int i = 0; i < BN / 32; ++i) {                                       \
            const int e = (i * 256 + wid * 64 + lane) * 8;                        \
            gload_lds16(Wg + (size_t)(e >> 6) * K + (k0_) + (e & 63),             \
                        &Bs[buf_][(size_t)(i * 256 + wid * 64) * 8]);             \
        }                                                                         \
    } while (0)

    const int nk = K / BK;
    G_STAGE(0, 0);
    __syncthreads();

    for (int ki = 0; ki < nk; ++ki) {
        const int cur = ki & 1;
        if (ki + 1 < nk) G_STAGE((ki + 1) * BK, cur ^ 1);   // overlaps compute

#pragma unroll
        for (int kk = 0; kk < BK; kk += 32) {
            bf16x8 af[MF], bf[NF];
#pragma unroll
            for (int m = 0; m < MF; ++m)
                af[m] = *(const bf16x8*)&As[cur][(wrow + m * 16 + lr) * BK + kk + lk];
#pragma unroll
            for (int n = 0; n < NF; ++n)
                bf[n] = *(const bf16x8*)&Bs[cur][(wcol + n * 16 + lr) * BK + kk + lk];
#pragma unroll
            for (int m = 0; m < MF; ++m)
#pragma unroll
                for (int n = 0; n < NF; ++n)
                    acc[m][n] = __builtin_amdgcn_mfma_f32_16x16x32_bf16(af[m], bf[n], acc[m][n], 0, 0, 0);
        }
        __syncthreads();   // drains stage(ki+1); WAR for next overwrite
    }
#undef G_STAGE

    const int orow0 = m0 + wrow + (lane >> 4) * 4;
    const int ocol0 = n0 + wcol + lr;
#pragma unroll
    for (int m = 0; m < MF; ++m)
#pragma unroll
        for (int n = 0; n < NF; ++n) {
            if (OUTMODE == 2) {
                const int nc = ocol0 + n * 16;
                const int mrow = orow0 + m * 16;
                unsigned short* dst = (unsigned short*)Cout
                    + (size_t)((mrow >> 11) * 16 + (nc >> 6)) * (64 * 2048)
                    + (size_t)(nc & 63) * 2048 + (mrow & 2047);
                ushort4v pv;
#pragma unroll
                for (int i = 0; i < 4; ++i) pv[i] = f2b(acc[m][n][i]);
                *(ushort4v*)dst = pv;
            } else {
#pragma unroll
                for (int i = 0; i < 4; ++i) {
                    const size_t idx = (size_t)(orow0 + m * 16 + i) * N + ocol0 + n * 16;
                    if (OUTMODE == 1) ((unsigned short*)Cout)[idx] = f2b(acc[m][n][i]);
                    else              ((float*)Cout)[idx] = acc[m][n][i];
                }
            }
        }
}

// ------- split-bf16 GEMM (qk projection), 2-phase dbuf, BM=BN=64 -------
__global__ __launch_bounds__(256) void gemm_split(const unsigned short* __restrict__ Ah,
                                                  const unsigned short* __restrict__ Al,
                                                  const unsigned short* __restrict__ Wh,
                                                  const unsigned short* __restrict__ Wl,
                                                  float* __restrict__ C,
                                                  int M, int N, int K) {
    constexpr int BM = 64, BN = 64, BK = 64;
    constexpr int MF = 2, NF = 2;
    __shared__ __align__(16) unsigned short Ahs[2][BM * BK];
    __shared__ __align__(16) unsigned short Als[2][BM * BK];
    __shared__ __align__(16) unsigned short Bhs[2][BN * BK];
    __shared__ __align__(16) unsigned short Bls[2][BN * BK];

    const int t = threadIdx.x;
    const int wid = t >> 6, lane = t & 63;
    const int m0 = blockIdx.x * BM, n0 = blockIdx.y * BN;
    const int wrow = (wid >> 1) * 32;
    const int wcol = (wid & 1) * 32;
    const int lr = lane & 15, lk = (lane >> 4) * 8;

    f32x4 acc[MF][NF];
#pragma unroll
    for (int m = 0; m < MF; ++m)
#pragma unroll
        for (int n = 0; n < NF; ++n) acc[m][n] = (f32x4){0.f, 0.f, 0.f, 0.f};

    const unsigned short* Ahg = Ah + (size_t)m0 * K;
    const unsigned short* Alg = Al + (size_t)m0 * K;
    const unsigned short* Whg = Wh + (size_t)n0 * K;
    const unsigned short* Wlg = Wl + (size_t)n0 * K;

#define S_STAGE(k0_, buf_)                                                        \
    do {                                                                          \
        _Pragma("unroll")                                                         \
        for (int i = 0; i < 2; ++i) {                                             \
            const int e = (i * 256 + wid * 64 + lane) * 8;                        \
            const size_t go = (size_t)(e >> 6) * K + (k0_) + (e & 63);            \
            const size_t lo = (size_t)(i * 256 + wid * 64) * 8;                   \
            gload_lds16(Ahg + go, &Ahs[buf_][lo]);                                \
            gload_lds16(Alg + go, &Als[buf_][lo]);                                \
            gload_lds16(Whg + go, &Bhs[buf_][lo]);                                \
            gload_lds16(Wlg + go, &Bls[buf_][lo]);                                \
        }                                                                         \
    } while (0)

    const int nk = K / BK;
    S_STAGE(0, 0);
    __syncthreads();

    for (int ki = 0; ki < nk; ++ki) {
        const int cur = ki & 1;
        if (ki + 1 < nk) S_STAGE((ki + 1) * BK, cur ^ 1);

#pragma unroll
        for (int kk = 0; kk < BK; kk += 32) {
            bf16x8 afh[MF], afl[MF], bfh[NF], bfl[NF];
#pragma unroll
            for (int m = 0; m < MF; ++m) {
                afh[m] = *(const bf16x8*)&Ahs[cur][(wrow + m * 16 + lr) * BK + kk + lk];
                afl[m] = *(const bf16x8*)&Als[cur][(wrow + m * 16 + lr) * BK + kk + lk];
            }
#pragma unroll
            for (int n = 0; n < NF; ++n) {
                bfh[n] = *(const bf16x8*)&Bhs[cur][(wcol + n * 16 + lr) * BK + kk + lk];
                bfl[n] = *(const bf16x8*)&Bls[cur][(wcol + n * 16 + lr) * BK + kk + lk];
            }
#pragma unroll
            for (int m = 0; m < MF; ++m)
#pragma unroll
                for (int n = 0; n < NF; ++n) {
                    acc[m][n] = __builtin_amdgcn_mfma_f32_16x16x32_bf16(afh[m], bfh[n], acc[m][n], 0, 0, 0);
                    acc[m][n] = __builtin_amdgcn_mfma_f32_16x16x32_bf16(afh[m], bfl[n], acc[m][n], 0, 0, 0);
                    acc[m][n] = __builtin_amdgcn_mfma_f32_16x16x32_bf16(afl[m], bfh[n], acc[m][n], 0, 0, 0);
                }
        }
        __syncthreads();
    }
#undef S_STAGE

    const int orow0 = m0 + wrow + (lane >> 4) * 4;
    const int ocol0 = n0 + wcol + lr;
#pragma unroll
    for (int m = 0; m < MF; ++m)
#pragma unroll
        for (int n = 0; n < NF; ++n)
#pragma unroll
            for (int i = 0; i < 4; ++i)
                C[(size_t)(orow0 + m * 16 + i) * N + ocol0 + n * 16] = acc[m][n][i];
}

// ---------------- f32 -> bf16 casts ----------------
__global__ __launch_bounds__(256) void cast_bf16(const float* __restrict__ in,
                                                 unsigned short* __restrict__ out, int n) {
    const int i = (blockIdx.x * 256 + threadIdx.x) * 8;
    if (i >= n) return;
    float4 a = *(const float4*)(in + i);
    float4 b = *(const float4*)(in + i + 4);
    ushort8 o;
    o[0] = f2b(a.x); o[1] = f2b(a.y); o[2] = f2b(a.z); o[3] = f2b(a.w);
    o[4] = f2b(b.x); o[5] = f2b(b.y); o[6] = f2b(b.z); o[7] = f2b(b.w);
    *(ushort8*)(out + i) = o;
}

__global__ __launch_bounds__(256) void cast_split(const float* __restrict__ in,
                                                  unsigned short* __restrict__ hi,
                                                  unsigned short* __restrict__ lo, int n) {
    const int i = (blockIdx.x * 256 + threadIdx.x) * 8;
    if (i >= n) return;
    float4 a = *(const float4*)(in + i);
    float4 b = *(const float4*)(in + i + 4);
    float xv[8] = {a.x, a.y, a.z, a.w, b.x, b.y, b.z, b.w};
    ushort8 oh, ol;
#pragma unroll
    for (int e = 0; e < 8; ++e) {
        const unsigned short h = f2b(xv[e]);
        oh[e] = h;
        ol[e] = f2b(xv[e] - b2f(h));
    }
    *(ushort8*)(hi + i) = oh;
    *(ushort8*)(lo + i) = ol;
}

// ------- feature map: qk_raw f32 -> q/k split hi|lo bf16 [bh][l][32] -------
__global__ __launch_bounds__(256) void ln_featuremap(const float* __restrict__ qk,
                                                     const float* __restrict__ gamma,
                                                     const float* __restrict__ beta,
                                                     unsigned short* __restrict__ qhl,
                                                     unsigned short* __restrict__ khl) {
    const int gid = blockIdx.x * 256 + threadIdx.x;
    const int idx = gid & 31;
    const int m = gid >> 5;
    const int b = m >> 11, l = m & 2047;
    const int h = idx & 15;
    const float scale = (idx < 16) ? 0.25f : 1.0f;
    const float* p = qk + (size_t)gid * 16;

    float xv[16];
    float4 v0 = *(const float4*)(p + 0);
    float4 v1 = *(const float4*)(p + 4);
    float4 v2 = *(const float4*)(p + 8);
    float4 v3 = *(const float4*)(p + 12);
    xv[0]=v0.x; xv[1]=v0.y; xv[2]=v0.z; xv[3]=v0.w;
    xv[4]=v1.x; xv[5]=v1.y; xv[6]=v1.z; xv[7]=v1.w;
    xv[8]=v2.x; xv[9]=v2.y; xv[10]=v2.z; xv[11]=v2.w;
    xv[12]=v3.x; xv[13]=v3.y; xv[14]=v3.z; xv[15]=v3.w;

    float mu = 0.f;
#pragma unroll
    for (int f = 0; f < 16; ++f) mu += xv[f];
    mu *= 0.0625f;
    float var = 0.f;
#pragma unroll
    for (int f = 0; f < 16; ++f) { float d = xv[f] - mu; var = fmaf(d, d, var); }
    var *= 0.0625f;
    const float rs = rsqrtf(var + 1e-5f);

    ushort8 hi0, hi1, lo0, lo1;
#pragma unroll
    for (int f = 0; f < 16; ++f) {
        const float v = ((xv[f] - mu) * rs * gamma[f] + beta[f]) * scale;
        const unsigned short hb = f2b(v);
        const unsigned short lb = f2b(v - b2f(hb));
        if (f < 8) { hi0[f] = hb; lo0[f] = lb; }
        else       { hi1[f - 8] = hb; lo1[f - 8] = lb; }
    }
    unsigned short* dst = ((idx < 16) ? qhl : khl)
        + ((size_t)(b * 16 + h) * 2048 + l) * 32;
    *(ushort8*)(dst + 0)  = hi0;
    *(ushort8*)(dst + 8)  = hi1;
    *(ushort8*)(dst + 16) = lo0;
    *(ushort8*)(dst + 24) = lo1;
}

// ------- causal (q.k)^2 attention: quad-tile blocks, XCD-colocated K/V -------
// grid (32, 8): x = bh (id%8 = bh%8 -> same-bh blocks on one XCD), y -> q-tiles
// {y, 15-y, 16+y, 31-y}. 1024 threads = 4 groups x 4 waves.
// Triple-buffered K/V, 2-ahead prefetch, counted vmcnt(1).
__global__ __launch_bounds__(1024) void rebased_attn(const unsigned short* __restrict__ qhl_g,
                                                     const unsigned short* __restrict__ khl_g,
                                                     const unsigned short* __restrict__ vT,
                                                     unsigned short* __restrict__ o) {
    const int bh = blockIdx.x;
    const int bb = bh >> 4;
    const int t = threadIdx.x;
    const int wid = t >> 6, lane = t & 63;
    const int g = wid >> 2, lw = wid & 3;   // group, wave-in-group
    const int fr = lane & 15;
    const int fg = lane >> 4;
    const int x = blockIdx.y;               // 0..7
    const int qt = (g == 0) ? x : (g == 1) ? (15 - x) : (g == 2) ? (16 + x) : (31 - x);
    const int qtmax = 31 - x;               // group 3 is always longest (>= 24)
    const int qbase = qt << 6;

    __shared__ __align__(16) unsigned short khl[3][4 * 64 * 8];   // 3 x 4KB
    __shared__ __align__(16) unsigned short vsl[3][8 * 64 * 8];   // 3 x 8KB
    __shared__ __align__(16) __bf16 P[256][72];                   // 36KB (per-wave rows)

    const unsigned short* qg  = qhl_g + (size_t)bh * 2048 * 32;
    const unsigned short* kg  = khl_g + (size_t)bh * 2048 * 32;
    const unsigned short* vbh = vT + (size_t)bh * 64 * 2048;
    unsigned short*       obh = o  + (size_t)bb * 2048 * 1024 + (bh & 15) * 64;

    const bf16x8 z8 = {(__bf16)0.f,(__bf16)0.f,(__bf16)0.f,(__bf16)0.f,
                       (__bf16)0.f,(__bf16)0.f,(__bf16)0.f,(__bf16)0.f};
    const f32x4 zc = (f32x4){0.f, 0.f, 0.f, 0.f};

    // Q B-fragments straight from global (per-lane, once):
    const unsigned short* qrow = qg + (size_t)(qbase + 16 * lw + fr) * 32;
    const bf16x8 bq1 = *(const bf16x8*)&qrow[(fg & 1) * 8];
    const bf16x8 bq2 = *(const bf16x8*)&qrow[((fg & 1) + 2) * 8];

    // staging: 12 chunks (K:4 + V:8) over waves 0..11, exactly 1 load-inst/wave
#define STAGE_KV(kt_, buf_)                                                           \
    do {                                                                              \
        if (wid < 4)                                                                  \
            gload_lds16(kg + ((size_t)((kt_) << 6) + lane) * 32 + wid * 8,            \
                        &khl[buf_][wid * 512]);                                       \
        else if (wid < 12)                                                            \
            gload_lds16(vbh + (size_t)lane * 2048 + ((kt_) << 6) + (wid - 4) * 8,     \
                        &vsl[buf_][(wid - 4) * 512]);                                 \
    } while (0)

    // prologue: stage kt=0 and kt=1; wait for kt=0 only (kt=1 keeps flying)
    STAGE_KV(0, 0);
    STAGE_KV(1, 1);
    asm volatile("s_waitcnt vmcnt(1)" ::: "memory");
    __builtin_amdgcn_s_barrier();

    f32x4 oacc[4];
#pragma unroll
    for (int n = 0; n < 4; ++n) oacc[n] = zc;
    float zlane = 0.f;

    for (int kt = 0; kt <= qtmax; ++kt) {
        const int cur = kt % 3;
        const bool pf = (kt + 2 <= qtmax);
        if (pf) STAGE_KV(kt + 2, (kt + 2) % 3);   // overlaps compute below

        if (kt <= qt) {   // wave-uniform: group still active
            const int prow = 64 * g + 16 * lw + fr;
            // phase 1: S^T strip = K(all 64) x Q(wave's 16 rows), hi/lo MFMA pair
#pragma unroll
            for (int nrow = 0; nrow < 4; ++nrow) {
                const bf16x8 ak  = *(const bf16x8*)&khl[cur][(fg * 64 + nrow * 16 + fr) * 8];
                const bf16x8 ak2 = (fg < 2) ? ak : z8;           // [kh|0]
                f32x4 s = __builtin_amdgcn_mfma_f32_16x16x32_bf16(ak2, bq2, zc, 0, 0, 0);
                s = __builtin_amdgcn_mfma_f32_16x16x32_bf16(ak, bq1, s, 0, 0, 0);

                float s2[4];
                if (kt == qt) {
                    const int qr = 16 * lw + fr;
                    const int kc = nrow * 16 + fg * 4;
#pragma unroll
                    for (int reg = 0; reg < 4; ++reg) {
                        float xs = s[reg];
                        float y = xs * xs;
                        s2[reg] = (kc + reg <= qr) ? y : 0.f;
                        zlane += s2[reg];
                    }
                } else {
#pragma unroll
                    for (int reg = 0; reg < 4; ++reg) {
                        float xs = s[reg];
                        s2[reg] = xs * xs;
                        zlane += s2[reg];
                    }
                }
                bf16x4 pv = {(__bf16)s2[0], (__bf16)s2[1], (__bf16)s2[2], (__bf16)s2[3]};
                *(bf16x4*)&P[prow][nrow * 16 + fg * 4] = pv;   // wave-private row
            }

            // phase 2: O strip += P_strip @ V (same-wave P, no extra barrier)
            const bf16x8 a0 = *(const bf16x8*)&P[prow][fg * 8];
            const bf16x8 a1 = *(const bf16x8*)&P[prow][32 + fg * 8];
#pragma unroll
            for (int nt = 0; nt < 4; ++nt) {
                const bf16x8 b0 = *(const bf16x8*)&vsl[cur][((fg    ) * 64 + nt * 16 + fr) * 8];
                const bf16x8 b1 = *(const bf16x8*)&vsl[cur][((fg + 4) * 64 + nt * 16 + fr) * 8];
                oacc[nt] = __builtin_amdgcn_mfma_f32_16x16x32_bf16(a0, b0, oacc[nt], 0, 0, 0);
                oacc[nt] = __builtin_amdgcn_mfma_f32_16x16x32_bf16(a1, b1, oacc[nt], 0, 0, 0);
            }
        }

        // counted wait: tile kt+1 (older load) must land; kt+2's load may fly
        if (pf) asm volatile("s_waitcnt vmcnt(1)" ::: "memory");
        else    asm volatile("s_waitcnt vmcnt(0)" ::: "memory");
        __builtin_amdgcn_s_barrier();
    }
#undef STAGE_KV

    // z: lanes {fr, fr+16, fr+32, fr+48} share q-row 16*lw+fr
    float z = zlane;
    z += __shfl_xor(z, 16);
    z += __shfl_xor(z, 32);
    const float zinv = 1.f / (z + 1e-5f);

    // epilogue: oacc D-layout row = fg*4+reg (q within 16), col = fr (d within nt)
#pragma unroll
    for (int reg = 0; reg < 4; ++reg) {
        const float r = __shfl(zinv, fg * 4 + reg);
        const size_t gro = (size_t)(qbase + 16 * lw + fg * 4 + reg) * 1024;
#pragma unroll
        for (int nt = 0; nt < 4; ++nt)
            obh[gro + nt * 16 + fr] = f2b(oacc[nt][reg] * r);
    }
}

extern "C" void kernel_launch(void* const* d_in, const int* in_sizes, int n_in,
                              void* d_out, int out_size, void* d_ws, size_t ws_size,
                              hipStream_t stream) {
    const float* x     = (const float*)d_in[0];
    const float* Wq    = (const float*)d_in[1];
    const float* Wk    = (const float*)d_in[2];
    const float* Wv    = (const float*)d_in[3];
    const float* Wo    = (const float*)d_in[4];
    const float* gamma = (const float*)d_in[5];
    const float* beta  = (const float*)d_in[6];
    float* out = (float*)d_out;
    (void)in_sizes; (void)n_in; (void)out_size; (void)ws_size;

    char* w = (char*)d_ws;
    float*          qk_raw = (float*)w;                                   // 8 MB @ 0
    unsigned short* vTb    = (unsigned short*)(w + (8u  << 20));          // 8 MB [bh][64][2048]
    unsigned short* ob     = (unsigned short*)(w + (16u << 20));          // 8 MB
    unsigned short* xh     = (unsigned short*)(w + (24u << 20));          // 8 MB (dead after gemms)
    unsigned short* xl     = (unsigned short*)(w + (32u << 20));          // 8 MB (dead after gemm_split)
    unsigned short* qhl_g  = (unsigned short*)(w + (24u << 20));          // 4 MB (overlays dead xh)
    unsigned short* khl_g  = (unsigned short*)(w + (28u << 20));          // 4 MB (overlays dead xh)
    unsigned short* wqkh   = (unsigned short*)(w + (40u << 20));          // 1 MB
    unsigned short* wqkl   = (unsigned short*)(w + (41u << 20));          // 1 MB
    unsigned short* wvb    = (unsigned short*)(w + (42u << 20));          // 2 MB
    unsigned short* wob    = (unsigned short*)(w + (44u << 20));          // 2 MB

    cast_split<<<2048, 256, 0, stream>>>(x,  xh, xl, 4096 * 1024);
    cast_split<<<128,  256, 0, stream>>>(Wq, wqkh, wqkl, 256 * 1024);
    cast_split<<<128,  256, 0, stream>>>(Wk, wqkh + 256 * 1024, wqkl + 256 * 1024, 256 * 1024);
    cast_bf16 <<<512,  256, 0, stream>>>(Wv, wvb, 1024 * 1024);
    cast_bf16 <<<512,  256, 0, stream>>>(Wo, wob, 1024 * 1024);

    // qk projection (split-bf16, ~fp32): [4096][512] f32
    gemm_split<<<dim3(64, 8), 256, 0, stream>>>(xh, xl, wqkh, wqkl, qk_raw, 4096, 512, 1024);
    // v projection -> transposed bf16 vT[bh][d][l]
    gemm_mfma<64, 64, 2><<<dim3(64, 16), 256, 0, stream>>>(xh, wvb, vTb, 4096, 1024, 1024);
    // feature map -> q/k hi|lo bf16 [bh][l][32]
    ln_featuremap<<<512, 256, 0, stream>>>(qk_raw, gamma, beta, qhl_g, khl_g);
    // attention -> bf16 ob; grid (32 bh, 8 quads): same-bh blocks share an XCD
    rebased_attn<<<dim3(32, 8), 1024, 0, stream>>>(qhl_g, khl_g, vTb, ob);
    // output projection -> f32 out
    gemm_mfma<64, 64, 0><<<dim3(64, 16), 256, 0, stream>>>(ob, wob, out, 4096, 1024, 1024);
}